// Round 15
// baseline (476.314 us; speedup 1.0000x reference)
//
#include <hip/hip_runtime.h>
#include <math.h>

// Problem constants (fixed by the reference)
#define NN   32768
#define BG   128
#define SG   256
#define EE   524288
#define DIN_ 128
#define DH_  256
#define NH   8
#define HD_  32
#define DFF_ 1024
#define EPS_ 1e-5f

typedef __attribute__((ext_vector_type(8))) short bf16x8;
typedef __attribute__((ext_vector_type(4))) float f32x4;
typedef __attribute__((ext_vector_type(2))) unsigned int u32x2;
typedef __attribute__((ext_vector_type(4))) unsigned int u32x4;

__device__ __forceinline__ unsigned short f2bf(float f) {
    unsigned int u = __builtin_bit_cast(unsigned int, f);
    unsigned int r = u + 0x7FFFu + ((u >> 16) & 1u);
    return (unsigned short)(r >> 16);
}
__device__ __forceinline__ float bf2f(unsigned short u) {
    return __builtin_bit_cast(float, (unsigned int)u << 16);
}
// Async global->LDS DMA, 16 B per lane (dest = wave-uniform base + lane*16).
__device__ __forceinline__ void glds16(const unsigned short* g, unsigned short* l) {
    __builtin_amdgcn_global_load_lds(
        (const __attribute__((address_space(1))) void*)g,
        (__attribute__((address_space(3))) void*)l, 16, 0, 0);
}
// s_waitcnt with vmcnt(N) only (exp/lgkm masked off).
#define WAIT_VM0() __builtin_amdgcn_s_waitcnt(0x0F70)
#define WAIT_VM2() __builtin_amdgcn_s_waitcnt(0x0F72)
#define WAIT_VM4() __builtin_amdgcn_s_waitcnt(0x0F74)
#define WAIT_VM6() __builtin_amdgcn_s_waitcnt(0x0F76)

// Softmax pre-scale: 1/sqrt(32) * log2(e), folded into wq/bq at transpose time.
#define QSCALE (0.17677669529663689f * 1.4426950408889634f)

// ---------------------------------------------------------------------------
// MEGA-PREP: all independent prologue work in ONE dispatch.
// blockIdx.y segments: 0-7 weight cast+transpose, 8 QKV bias concat,
// 9 edge-degree histogram, 10 fused init_avg_h + BN1 stats + out-zeroing.
struct PrepArgs {
    const float* w[8];
    unsigned short* o[8];
    int K[8];
    int N[8];
    float s[8];
    const float* bq;
    const float* bk;
    const float* bv;
    float* bqkv;
    const int* col;      // edge targets
    int* deg;
    const float* X;      // raw x
    float* out2;         // init_avg_h target
    float* outz;         // readout atomics target (zeroed here)
    float* csum;
    float* csumsq;
};
__global__ __launch_bounds__(256) void prep_kernel(PrepArgs a) {
    int seg = blockIdx.y;
    int idx = blockIdx.x * 256 + threadIdx.x;
    if (seg < 8) {
        int K = a.K[seg], N = a.N[seg];
        if (idx < K * N) {
            int n = idx / K, k = idx - n * K;
            a.o[seg][idx] = f2bf(a.w[seg][(size_t)k * N + n] * a.s[seg]);
        }
    } else if (seg == 8) {
        if (idx < 256) a.bqkv[idx] = a.bq[idx] * QSCALE;
        else if (idx < 512) a.bqkv[idx] = a.bk[idx - 256];
        else if (idx < 768) a.bqkv[idx] = a.bv[idx - 512];
    } else if (seg == 9) {
        if (idx < EE) atomicAdd(&a.deg[a.col[idx]], 1);
    } else {
        int b = blockIdx.x, j = threadIdx.x;
        if (b < BG && j < 128) {
            a.outz[b * 256 + j] = 0.f;
            a.outz[b * 256 + 128 + j] = 0.f;
            float s = 0.f, sq = 0.f;
            for (int r = 0; r < SG; ++r) {
                float v = a.X[(size_t)(b * SG + r) * DIN_ + j];
                s += v; sq += v * v;
            }
            a.out2[b * DIN_ + j] = s * (1.f / (float)SG);
            atomicAdd(&a.csum[j], s);
            atomicAdd(&a.csumsq[j], sq);
        }
    }
}

// ---------------------------------------------------------------------------
// Fused CSR-scan (block 0) + BN1 apply (blocks 1..1024), 1024 threads.
__global__ __launch_bounds__(1024) void scanbn_kernel(
    const int* __restrict__ deg, int* __restrict__ off, float* __restrict__ dis,
    const float* __restrict__ X,
    const float* __restrict__ csum, const float* __restrict__ csumsq,
    const float* __restrict__ g, const float* __restrict__ b,
    unsigned short* __restrict__ Y) {
    __shared__ int sums[1024];
    if (blockIdx.x == 0) {
        int t = threadIdx.x;
        int base = t * 32;
        int loc[32];
        int run = 0;
#pragma unroll
        for (int i = 0; i < 32; ++i) { loc[i] = run; run += deg[base + i]; }
        sums[t] = run;
        __syncthreads();
        for (int d = 1; d < 1024; d <<= 1) {
            int tmp = (t >= d) ? sums[t - d] : 0;
            __syncthreads();
            sums[t] += tmp;
            __syncthreads();
        }
        int excl = sums[t] - run;
#pragma unroll
        for (int i = 0; i < 32; ++i) {
            off[base + i] = excl + loc[i];
            dis[base + i] = rsqrtf((float)(deg[base + i] + 1));
        }
        if (t == 1023) off[NN] = sums[1023];
    } else {
        int i4 = ((blockIdx.x - 1) * 1024 + threadIdx.x) * 4;
        int j = i4 & (DIN_ - 1);
        float4 v  = *(const float4*)(X + i4);
        float4 cs = *(const float4*)(csum + j);
        float4 cq = *(const float4*)(csumsq + j);
        float4 gg = *(const float4*)(g + j);
        float4 bb = *(const float4*)(b + j);
        unsigned short o[4];
        {
            float mu = cs.x * (1.f / (float)NN);
            float sc = gg.x * rsqrtf(cq.x * (1.f / (float)NN) - mu * mu + EPS_);
            o[0] = f2bf(v.x * sc + (bb.x - mu * sc));
        }
        {
            float mu = cs.y * (1.f / (float)NN);
            float sc = gg.y * rsqrtf(cq.y * (1.f / (float)NN) - mu * mu + EPS_);
            o[1] = f2bf(v.y * sc + (bb.y - mu * sc));
        }
        {
            float mu = cs.z * (1.f / (float)NN);
            float sc = gg.z * rsqrtf(cq.z * (1.f / (float)NN) - mu * mu + EPS_);
            o[2] = f2bf(v.z * sc + (bb.z - mu * sc));
        }
        {
            float mu = cs.w * (1.f / (float)NN);
            float sc = gg.w * rsqrtf(cq.w * (1.f / (float)NN) - mu * mu + EPS_);
            o[3] = f2bf(v.w * sc + (bb.w - mu * sc));
        }
        *(uint2*)(Y + i4) = *(uint2*)o;
    }
}

__global__ __launch_bounds__(256) void scatter_kernel(const int* __restrict__ row,
                                                      const int* __restrict__ col,
                                                      const int* __restrict__ off,
                                                      int* __restrict__ cnt,
                                                      int* __restrict__ srow) {
    int e = blockIdx.x * 256 + threadIdx.x;
    if (e < EE) {
        int c = col[e];
        int p = off[c] + atomicAdd(&cnt[c], 1);
        srow[p] = row[e];
    }
}

// ---------------------------------------------------------------------------
// bf16 GCN aggregation, 4x-unrolled edge loop for MLP.
// FUSE_BN path computes BN scale/shift INLINE from column stats.
template <int C, int FUSE_BN>
__global__ __launch_bounds__(256) void aggb_kernel(const unsigned short* __restrict__ X,
                                                   const int* __restrict__ off,
                                                   const int* __restrict__ srow,
                                                   const float* __restrict__ dis,
                                                   const float* __restrict__ csum,
                                                   const float* __restrict__ csumsq,
                                                   const float* __restrict__ bg,
                                                   const float* __restrict__ bb,
                                                   unsigned short* __restrict__ Y) {
    constexpr int EPL = C / 64;
    int lane = threadIdx.x & 63;
    int c = blockIdx.x * 4 + (threadIdx.x >> 6);
    float dc = dis[c];
    float acc[EPL];
    float wsum = dc;
    {
        unsigned short t[EPL];
        const unsigned short* xc = X + (size_t)c * C + lane * EPL;
        if constexpr (EPL == 4) *(uint2*)t = *(const uint2*)xc;
        else *(unsigned int*)t = *(const unsigned int*)xc;
#pragma unroll
        for (int e2 = 0; e2 < EPL; ++e2) acc[e2] = dc * bf2f(t[e2]);
    }
    int s = off[c], en = off[c + 1];
    int i = s;
    for (; i + 4 <= en; i += 4) {
        int r0 = srow[i], r1 = srow[i + 1], r2 = srow[i + 2], r3 = srow[i + 3];
        float d0 = dis[r0], d1 = dis[r1], d2 = dis[r2], d3 = dis[r3];
        unsigned short t0[EPL], t1[EPL], t2[EPL], t3[EPL];
        const unsigned short* p0 = X + (size_t)r0 * C + lane * EPL;
        const unsigned short* p1 = X + (size_t)r1 * C + lane * EPL;
        const unsigned short* p2 = X + (size_t)r2 * C + lane * EPL;
        const unsigned short* p3 = X + (size_t)r3 * C + lane * EPL;
        if constexpr (EPL == 4) {
            *(uint2*)t0 = *(const uint2*)p0;
            *(uint2*)t1 = *(const uint2*)p1;
            *(uint2*)t2 = *(const uint2*)p2;
            *(uint2*)t3 = *(const uint2*)p3;
        } else {
            *(unsigned int*)t0 = *(const unsigned int*)p0;
            *(unsigned int*)t1 = *(const unsigned int*)p1;
            *(unsigned int*)t2 = *(const unsigned int*)p2;
            *(unsigned int*)t3 = *(const unsigned int*)p3;
        }
        wsum += d0 + d1 + d2 + d3;
#pragma unroll
        for (int e2 = 0; e2 < EPL; ++e2) {
            acc[e2] += d0 * bf2f(t0[e2]) + d1 * bf2f(t1[e2]) +
                       d2 * bf2f(t2[e2]) + d3 * bf2f(t3[e2]);
        }
    }
    for (; i < en; ++i) {
        int r = srow[i];
        float dr = dis[r];
        unsigned short t[EPL];
        const unsigned short* xr = X + (size_t)r * C + lane * EPL;
        if constexpr (EPL == 4) *(uint2*)t = *(const uint2*)xr;
        else *(unsigned int*)t = *(const unsigned int*)xr;
        wsum += dr;
#pragma unroll
        for (int e2 = 0; e2 < EPL; ++e2) acc[e2] += dr * bf2f(t[e2]);
    }
    unsigned short t[EPL];
#pragma unroll
    for (int e2 = 0; e2 < EPL; ++e2) {
        float v;
        if constexpr (FUSE_BN) {
            int j = lane * EPL + e2;
            float mu = csum[j] * (1.f / (float)NN);
            float var = csumsq[j] * (1.f / (float)NN) - mu * mu;
            float sc = bg[j] * rsqrtf(var + EPS_);
            float sh = bb[j] - mu * sc;
            v = dc * (sc * acc[e2] + sh * wsum);
        } else {
            v = dc * acc[e2];
        }
        t[e2] = f2bf(v);
    }
    unsigned short* yc = Y + (size_t)c * C + lane * EPL;
    if constexpr (EPL == 4) *(uint2*)yc = *(const uint2*)t;
    else *(unsigned int*)yc = *(const unsigned int*)t;
}

// ---------------------------------------------------------------------------
// MT=128 bf16 MFMA GEMM (QKV / ff1), proven round-5 structure: triple-buffered
// glds staging (depth-2 in flight, counted vmcnt), raw s_barrier, XCD swizzle,
// XOR-swizzled staging, coalesced LDS C-tile epilogue. 48 KB -> 3 blocks/CU.
__global__ __launch_bounds__(512, 8) void gemm_bf16_kernel(
    const unsigned short* __restrict__ A,
    const unsigned short* __restrict__ Bt,
    unsigned short* __restrict__ Cb,
    int M, int K, int N,
    const float* __restrict__ bias,
    const unsigned short* __restrict__ resb,
    const float* __restrict__ inter,
    int do_relu, int relu_first) {
    constexpr int LDP = 32;
    constexpr int CP = 136;
    constexpr int MI = 2;
    constexpr int STG = 8192;                // per-stage shorts: A 8KB | B 8KB
    constexpr int BOFS = 4096;
    __shared__ unsigned short Smem[3 * STG];
    unsigned short* Cs = Smem;               // union: staging dead after K-loop
    int gx = gridDim.x, gyP = gridDim.y >> 3;
    int d = blockIdx.y * gx + blockIdx.x;
    int xcd = d & 7, j2 = d >> 3;
    int bm = (xcd * gyP + j2 / gx) * 128;
    int bn = (j2 % gx) * 128;
    int tid = threadIdx.x;
    int wave = tid >> 6, lane = tid & 63;
    int wm = (wave >> 1) * 32;               // 4 m-waves x 2 n-waves
    int wn = (wave & 1) * 64;
    int lrc = lane & 15;
    int koct = lane >> 4;
    int rsw = (lrc >> 1) & 3;
    int rofs = (koct ^ rsw) * 8;
    int cg = (lane & 3) ^ ((lane >> 3) & 3);
    int skk = cg * 8;

    int sr = wave * 16 + (lane >> 2);
    const unsigned short* gA0 = A + (size_t)(bm + sr) * K + skk;
    const unsigned short* gB0 = Bt + (size_t)(bn + sr) * K + skk;
    int lofs = wave * 512 + lane * 8;

    f32x4 acc[MI][4];
#pragma unroll
    for (int i = 0; i < MI; ++i)
#pragma unroll
        for (int j = 0; j < 4; ++j) acc[i][j] = (f32x4){0.f, 0.f, 0.f, 0.f};

    glds16(gA0, Smem + lofs);
    glds16(gB0, Smem + BOFS + lofs);
    glds16(gA0 + 32, Smem + STG + lofs);
    glds16(gB0 + 32, Smem + STG + BOFS + lofs);

    int rb = 0;
    for (int k0 = 0; k0 < K; k0 += 32) {
        if (k0 + 64 < K) {
            int wb = rb + 2; if (wb >= 3) wb -= 3;
            unsigned short* ld = Smem + wb * STG;
            glds16(gA0 + k0 + 64, ld + lofs);
            glds16(gB0 + k0 + 64, ld + BOFS + lofs);
            WAIT_VM4();                       // drain stage t; t+1,t+2 in flight
        } else if (k0 + 32 < K) {
            WAIT_VM2();
        } else {
            WAIT_VM0();
        }
        __builtin_amdgcn_s_barrier();
        const unsigned short* Ab = Smem + rb * STG;
        const unsigned short* Bb = Ab + BOFS;
        bf16x8 af[MI], bfr[4];
#pragma unroll
        for (int i = 0; i < MI; ++i)
            af[i] = *(const bf16x8*)(Ab + (wm + i * 16 + lrc) * LDP + rofs);
#pragma unroll
        for (int j = 0; j < 4; ++j)
            bfr[j] = *(const bf16x8*)(Bb + (wn + j * 16 + lrc) * LDP + rofs);
#pragma unroll
        for (int i = 0; i < MI; ++i)
#pragma unroll
            for (int j = 0; j < 4; ++j)
                acc[i][j] = __builtin_amdgcn_mfma_f32_16x16x32_bf16(af[i], bfr[j],
                                                                    acc[i][j], 0, 0, 0);
        __builtin_amdgcn_s_barrier();
        rb = (rb + 1 == 3) ? 0 : rb + 1;
    }
#pragma unroll
    for (int i = 0; i < MI; ++i) {
#pragma unroll
        for (int r = 0; r < 4; ++r) {
            int lrow = wm + i * 16 + koct * 4 + r;
            int grow = bm + lrow;
#pragma unroll
            for (int j = 0; j < 4; ++j) {
                int lcol = wn + j * 16 + lrc;
                int gcol = bn + lcol;
                float v = acc[i][j][r];
                if (bias) v += bias[gcol];
                if (relu_first) v = fmaxf(v, 0.f);
                if (resb) v += bf2f(resb[(size_t)grow * N + gcol]);
                if (inter) v += inter[(grow >> 8) * N + gcol];
                if (do_relu && !relu_first) v = fmaxf(v, 0.f);
                Cs[lrow * CP + lcol] = f2bf(v);
            }
        }
    }
    __syncthreads();
#pragma unroll
    for (int it = 0; it < 4; ++it) {
        int row = it * 32 + (tid >> 4);
        int cc = (tid & 15) * 8;
        *(uint4*)(&Cb[(size_t)(bm + row) * N + bn + cc]) =
            *(const uint4*)(&Cs[row * CP + cc]);
    }
}

// ---------------------------------------------------------------------------
// 64x256 full-row-tile bf16 GEMM for N=256 layers (round-27 structure, kept).
// K-STEP = 64 double-buffered (2 x 40 KB = 80 KB = the 2-block/CU grid cap).
// Per step: 16 MFMA + 12 ds_read per wave; 8 waves x 32x64 wave-tile.
// Fusion modes:
//   MODE 0: plain copy-out                       (conv2)
//   MODE 1: copy-out + BN column-stats atomics   (conv1)
//   MODE 2: row LayerNorm -> write Cb            (oproj, in-place safe)
//   MODE 3: row LayerNorm -> column-sum atomics into outp (ff2+readout)
template <int MODE>
__global__ __launch_bounds__(512, 2) void gemm64n256_kernel(
    const unsigned short* __restrict__ A,
    const unsigned short* __restrict__ Bt,
    unsigned short* __restrict__ Cb,
    int K,
    const float* __restrict__ bias,
    const unsigned short* __restrict__ resb,
    const float* __restrict__ inter,
    int do_relu, int relu_first,
    float* __restrict__ stat0, float* __restrict__ stat1,
    const float* __restrict__ lng, const float* __restrict__ lnbt,
    float* __restrict__ outp) {
    constexpr int LDP = 32;
    constexpr int CP = 264;                  // 256 + 8 pad
    constexpr int STG = 20480;               // shorts per 64-k stage (40 KB)
    constexpr int AOFS1 = 2048;              // A chunk1
    constexpr int BOFS = 4096;               // B chunk0
    constexpr int BOFS1 = 12288;             // B chunk1
    __shared__ unsigned short Smem[2 * STG]; // 80 KB -> 2 blocks/CU (= grid cap)
    unsigned short* Cs = Smem;               // union (64*264 = 16896 shorts)
    int bm = blockIdx.x * 64;
    int tid = threadIdx.x;
    int wave = tid >> 6, lane = tid & 63;
    int wm = (wave >> 2) * 32;               // 2 m-waves x 4 n-waves
    int wn = (wave & 3) * 64;
    int lrc = lane & 15;
    int koct = lane >> 4;
    int rsw = (lrc >> 1) & 3;
    int rofs = (koct ^ rsw) * 8;
    int cg = (lane & 3) ^ ((lane >> 3) & 3);
    int skk = cg * 8;

    const unsigned short* gB0 = Bt + (size_t)(wave * 32 + (lane >> 2)) * K + skk;
    size_t g16 = (size_t)16 * K;
    int lofsB = BOFS + wave * 1024 + lane * 8;
    const unsigned short* gA0 = nullptr;
    int lofsA = 0;
    if (wave < 4) {
        gA0 = A + (size_t)(bm + wave * 16 + (lane >> 2)) * K + skk;
        lofsA = wave * 512 + lane * 8;
    }

    f32x4 acc[2][4];
#pragma unroll
    for (int i = 0; i < 2; ++i)
#pragma unroll
        for (int j = 0; j < 4; ++j) acc[i][j] = (f32x4){0.f, 0.f, 0.f, 0.f};

    // prologue: stage 0 (k 0..63) into buf 0
    glds16(gB0, Smem + lofsB);
    glds16(gB0 + g16, Smem + lofsB + 512);
    glds16(gB0 + 32, Smem + (BOFS1 - BOFS) + lofsB);
    glds16(gB0 + 32 + g16, Smem + (BOFS1 - BOFS) + lofsB + 512);
    if (wave < 4) {
        glds16(gA0, Smem + lofsA);
        glds16(gA0 + 32, Smem + AOFS1 + lofsA);
    }

    int cur = 0;
    for (int k0 = 0; k0 < K; k0 += 64) {
        int nk = k0 + 64;
        if (nk < K) {
            unsigned short* nb = Smem + (cur ^ 1) * STG;
            glds16(gB0 + nk, nb + lofsB);
            glds16(gB0 + nk + g16, nb + lofsB + 512);
            glds16(gB0 + nk + 32, nb + (BOFS1 - BOFS) + lofsB);
            glds16(gB0 + nk + 32 + g16, nb + (BOFS1 - BOFS) + lofsB + 512);
            if (wave < 4) {
                glds16(gA0 + nk, nb + lofsA);
                glds16(gA0 + nk + 32, nb + AOFS1 + lofsA);
                WAIT_VM6();                  // stage t done; t+1 (6) in flight
            } else {
                WAIT_VM4();
            }
        } else {
            WAIT_VM0();
        }
        __builtin_amdgcn_s_barrier();
        const unsigned short* Sb = Smem + cur * STG;
#pragma unroll
        for (int kk = 0; kk < 2; ++kk) {
            const unsigned short* Ab = Sb + kk * AOFS1;
            const unsigned short* Bb = Sb + BOFS + kk * (BOFS1 - BOFS);
            bf16x8 af[2], bfr[4];
#pragma unroll
            for (int i = 0; i < 2; ++i)
                af[i] = *(const bf16x8*)(Ab + (wm + i * 16 + lrc) * LDP + rofs);
#pragma unroll
            for (int j = 0; j < 4; ++j)
                bfr[j] = *(const bf16x8*)(Bb + (wn + j * 16 + lrc) * LDP + rofs);
#pragma unroll
            for (int i = 0; i < 2; ++i)
#pragma unroll
                for (int j = 0; j < 4; ++j)
                    acc[i][j] = __builtin_amdgcn_mfma_f32_16x16x32_bf16(af[i], bfr[j],
                                                                        acc[i][j], 0, 0, 0);
        }
        __builtin_amdgcn_s_barrier();
        cur ^= 1;
    }
    // Finalize into Cs (bias/relu/res/inter applied in regs).
#pragma unroll
    for (int i = 0; i < 2; ++i) {
#pragma unroll
        for (int r = 0; r < 4; ++r) {
            int lrow = wm + i * 16 + koct * 4 + r;
            int grow = bm + lrow;
#pragma unroll
            for (int j = 0; j < 4; ++j) {
                int lcol = wn + j * 16 + lrc;
                float v = acc[i][j][r];
                if (bias) v += bias[lcol];
                if (relu_first) v = fmaxf(v, 0.f);
                if (resb) v += bf2f(resb[(size_t)grow * 256 + lcol]);
                if (inter) v += inter[(grow >> 8) * 256 + lcol];
                if (do_relu && !relu_first) v = fmaxf(v, 0.f);
                Cs[lrow * CP + lcol] = f2bf(v);
            }
        }
    }
    __syncthreads();

    if constexpr (MODE == 0 || MODE == 1) {
        // Coalesced copy-out: 4 iters x 16 rows; one uint4 per thread.
#pragma unroll
        for (int it = 0; it < 4; ++it) {
            int row = it * 16 + (tid >> 5);
            int cc = (tid & 31) * 8;
            *(uint4*)(&Cb[(size_t)(bm + row) * 256 + cc]) =
                *(const uint4*)(&Cs[row * CP + cc]);
        }
        if constexpr (MODE == 1) {
            if (tid < 256) {
                float s = 0.f, sq = 0.f;
                for (int r = 0; r < 64; ++r) {
                    float v = bf2f(Cs[r * CP + tid]);
                    s += v; sq += v * v;
                }
                atomicAdd(&stat0[tid], s);
                atomicAdd(&stat1[tid], sq);
            }
        }
    } else {
        // LN modes: wave handles rows [wave*8, wave*8+8), lane owns cols lane*4..+3.
        float4 g4 = *(const float4*)(lng + lane * 4);
        float4 b4 = *(const float4*)(lnbt + lane * 4);
#pragma unroll
        for (int q = 0; q < 8; ++q) {
            int row = wave * 8 + q;
            unsigned short tv[4];
            *(uint2*)tv = *(const uint2*)(Cs + row * CP + lane * 4);
            float v0 = bf2f(tv[0]), v1 = bf2f(tv[1]), v2 = bf2f(tv[2]), v3 = bf2f(tv[3]);
            float sum = v0 + v1 + v2 + v3;
#pragma unroll
            for (int off = 32; off; off >>= 1) sum += __shfl_xor(sum, off);
            float mu = sum * (1.f / (float)DH_);
            float d0 = v0 - mu, d1 = v1 - mu, d2 = v2 - mu, d3 = v3 - mu;
            float vs = d0 * d0 + d1 * d1 + d2 * d2 + d3 * d3;
#pragma unroll
            for (int off = 32; off; off >>= 1) vs += __shfl_xor(vs, off);
            float rs = rsqrtf(vs * (1.f / (float)DH_) + EPS_);
            unsigned short ov[4];
            ov[0] = f2bf(d0 * rs * g4.x + b4.x);
            ov[1] = f2bf(d1 * rs * g4.y + b4.y);
            ov[2] = f2bf(d2 * rs * g4.z + b4.z);
            ov[3] = f2bf(d3 * rs * g4.w + b4.w);
            if constexpr (MODE == 2) {
                *(uint2*)(&Cb[(size_t)(bm + row) * 256 + lane * 4]) = *(uint2*)ov;
            } else {
                *(uint2*)(Cs + row * CP + lane * 4) = *(uint2*)ov;
            }
        }
        if constexpr (MODE == 3) {
            __syncthreads();
            if (tid < 256) {
                float s = 0.f;
                for (int r = 0; r < 64; ++r) s += bf2f(Cs[r * CP + tid]);
                atomicAdd(&outp[(bm >> 8) * 256 + tid], s);
            }
        }
    }
}

// ---------------------------------------------------------------------------
// MFMA flash attention, transposed-score, no online softmax.
// P kept fully in-register: QK^T C-fragment -> v_cvt_pk_bf16_f32 ->
// permlane32_swap + permlane16_swap -> PV A-fragment. No Ps LDS buffer.
__global__ __launch_bounds__(256, 4) void attn_mfma_kernel(
    const unsigned short* __restrict__ QKV,
    unsigned short* __restrict__ Ob) {
    int b = blockIdx.x >> 3, h = blockIdx.x & 7;
    __shared__ unsigned short Ks[256 * 32];    // XOR-swizzled chunks
    __shared__ unsigned short Vt[32 * 264];    // [d][key 256 + pad]
    __shared__ float Lc[4 * 64];               // per-wave l broadcast
    const unsigned short* kg = QKV + (size_t)b * 256 * 768 + 256 + h * 32;
    const unsigned short* vg = QKV + (size_t)b * 256 * 768 + 512 + h * 32;
    int tid = threadIdx.x;
#pragma unroll
    for (int it = 0; it < 4; ++it) {
        int c = it * 256 + tid;
        int row = c >> 2, ch = c & 3;
        int slot = ch ^ ((row >> 1) & 3);
        *(uint4*)(Ks + row * 32 + slot * 8) =
            *(const uint4*)(kg + (size_t)row * 768 + ch * 8);
    }
#pragma unroll
    for (int it = 0; it < 4; ++it) {
        int c = it * 256 + tid;
        int key = c >> 2, d0 = (c & 3) * 8;
        unsigned short tmp[8];
        *(uint4*)tmp = *(const uint4*)(vg + (size_t)key * 768 + d0);
#pragma unroll
        for (int j = 0; j < 8; ++j) Vt[(d0 + j) * 264 + key] = tmp[j];
    }
    __syncthreads();

    int wave = tid >> 6, lane = tid & 63;
    int lr = lane & 15, koct = lane >> 4;
    int s4 = (lr >> 1) & 3;
    int qrow0 = b * 256 + wave * 64;
    bf16x8 qf[4];
#pragma unroll
    for (int j = 0; j < 4; ++j)
        qf[j] = *(const bf16x8*)(QKV + (size_t)(qrow0 + j * 16 + lr) * 768 + h * 32 + koct * 8);

    f32x4 Oa[4][2];
    float lp[4];
#pragma unroll
    for (int i = 0; i < 4; ++i) {
        Oa[i][0] = (f32x4){0.f, 0.f, 0.f, 0.f};
        Oa[i][1] = (f32x4){0.f, 0.f, 0.f, 0.f};
        lp[i] = 0.f;
    }
    float* Lw = Lc + wave * 64;

    for (int kc = 0; kc < 256; kc += 32) {
        bf16x8 kf0 = *(const bf16x8*)(Ks + (kc + lr) * 32 + (koct ^ s4) * 8);
        bf16x8 kf1 = *(const bf16x8*)(Ks + (kc + 16 + lr) * 32 + (koct ^ s4) * 8);
        bf16x8 pfr[4];
#pragma unroll
        for (int j = 0; j < 4; ++j) {
            f32x4 St0 = __builtin_amdgcn_mfma_f32_16x16x32_bf16(kf0, qf[j],
                            (f32x4){0.f, 0.f, 0.f, 0.f}, 0, 0, 0);
            f32x4 St1 = __builtin_amdgcn_mfma_f32_16x16x32_bf16(kf1, qf[j],
                            (f32x4){0.f, 0.f, 0.f, 0.f}, 0, 0, 0);
            float p0[4], p1[4], ps = 0.f;
#pragma unroll
            for (int r = 0; r < 4; ++r) {
                p0[r] = exp2f(St0[r]); p1[r] = exp2f(St1[r]);
                ps += p0[r] + p1[r];
            }
            lp[j] += ps;
            unsigned int w0a, w0b, w1a, w1b;
            asm("v_cvt_pk_bf16_f32 %0, %1, %2" : "=v"(w0a) : "v"(p0[0]), "v"(p0[1]));
            asm("v_cvt_pk_bf16_f32 %0, %1, %2" : "=v"(w0b) : "v"(p0[2]), "v"(p0[3]));
            asm("v_cvt_pk_bf16_f32 %0, %1, %2" : "=v"(w1a) : "v"(p1[0]), "v"(p1[1]));
            asm("v_cvt_pk_bf16_f32 %0, %1, %2" : "=v"(w1b) : "v"(p1[2]), "v"(p1[3]));
            u32x2 sa = __builtin_amdgcn_permlane32_swap(w0a, w1a, false, false);
            u32x2 da = __builtin_amdgcn_permlane16_swap(sa[0], sa[1], false, false);
            u32x2 sb = __builtin_amdgcn_permlane32_swap(w0b, w1b, false, false);
            u32x2 db = __builtin_amdgcn_permlane16_swap(sb[0], sb[1], false, false);
            u32x4 pw = {da[0], db[0], da[1], db[1]};
            pfr[j] = __builtin_bit_cast(bf16x8, pw);
        }
        bf16x8 vf0 = *(const bf16x8*)(Vt + lr * 264 + kc + koct * 8);
        bf16x8 vf1 = *(const bf16x8*)(Vt + (16 + lr) * 264 + kc + koct * 8);
#pragma unroll
        for (int i = 0; i < 4; ++i) {
            Oa[i][0] = __builtin_amdgcn_mfma_f32_16x16x32_bf16(pfr[i], vf0, Oa[i][0], 0, 0, 0);
            Oa[i][1] = __builtin_amdgcn_mfma_f32_16x16x32_bf16(pfr[i], vf1, Oa[i][1], 0, 0, 0);
        }
    }
#pragma unroll
    for (int j = 0; j < 4; ++j) {
        lp[j] += __shfl_xor(lp[j], 16);
        lp[j] += __shfl_xor(lp[j], 32);
    }
    if (koct == 0) {
#pragma unroll
        for (int j = 0; j < 4; ++j) Lw[j * 16 + lr] = lp[j];
    }
    __builtin_amdgcn_s_waitcnt(0);
#pragma unroll
    for (int i = 0; i < 4; ++i) {
        f32x4 l4 = *(const f32x4*)(Lw + i * 16 + koct * 4);
#pragma unroll
        for (int r = 0; r < 4; ++r) {
            float inv = 1.f / l4[r];
            int row = qrow0 + i * 16 + koct * 4 + r;
#pragma unroll
            for (int jn = 0; jn < 2; ++jn) {
                int col = h * 32 + jn * 16 + lr;
                Ob[(size_t)row * 256 + col] = f2bf(Oa[i][jn][r] * inv);
            }
        }
    }
}

// ---------------------------------------------------------------------------
extern "C" void kernel_launch(void* const* d_in, const int* in_sizes, int n_in,
                              void* d_out, int out_size, void* d_ws, size_t ws_size,
                              hipStream_t stream) {
    const float* x       = (const float*)d_in[0];
    const int*   ei      = (const int*)d_in[1];
    const float* inter_f = (const float*)d_in[3];
    const float* bn1_g = (const float*)d_in[4],  *bn1_b = (const float*)d_in[5];
    const float* bn2_g = (const float*)d_in[6],  *bn2_b = (const float*)d_in[7];
    const float* w_conv1 = (const float*)d_in[8],  *b_conv1 = (const float*)d_in[9];
    const float* w_conv2 = (const float*)d_in[10], *b_conv2 = (const float*)d_in[11];
    const float* wq = (const float*)d_in[12], *bq = (const float*)d_in[13];
    const float* wk = (const float*)d_in[14], *bk = (const float*)d_in[15];
    const float* wv = (const float*)d_in[16], *bv = (const float*)d_in[17];
    const float* wo = (const float*)d_in[18], *bo = (const float*)d_in[19];
    const float* ln1_g = (const float*)d_in[20], *ln1_b = (const float*)d_in[21];
    const float* ln2_g = (const float*)d_in[22], *ln2_b = (const float*)d_in[23];
    const float* w_ff1 = (const float*)d_in[24], *b_ff1 = (const float*)d_in[25];
    const float* w_ff2 = (const float*)d_in[26], *b_ff2 = (const float*)d_in[27];
    float* out = (float*)d_out;

    char* base = (char*)d_ws;
    size_t o = 0;
    auto alloc = [&](size_t bytes) -> void* {
        void* p = base + o;
        o = (o + bytes + 255) & ~(size_t)255;
        return p;
    };
    // Zero-init region first (contiguous: deg | cnt | csum | csumsq | csum2 | csumsq2)
    int*   deg    = (int*)alloc(NN * 4);
    int*   cnt    = (int*)alloc(NN * 4);
    float* csum   = (float*)alloc(256 * 4);
    float* csumsq = (float*)alloc(256 * 4);
    float* csum2  = (float*)alloc(256 * 4);
    float* csumsq2= (float*)alloc(256 * 4);
    int*   off    = (int*)alloc((NN + 1) * 4);
    int*   srow   = (int*)alloc(EE * 4);
    float* dis    = (float*)alloc(NN * 4);
    float* bqkv   = (float*)alloc(768 * 4);
    const size_t SLOT = (size_t)NN * DH_;  // 8M elements (16 MB bf16)
    unsigned short* Arena = (unsigned short*)alloc((size_t)NN * DFF_ * 2);
    unsigned short* TB = (unsigned short*)alloc(SLOT * 2);  // tb
    unsigned short* B0 = (unsigned short*)alloc(SLOT * 2);  // Xb->h1b->Ob->t2b
    unsigned short* wc1t  = (unsigned short*)alloc((size_t)DIN_ * DH_ * 2);
    unsigned short* wc2t  = (unsigned short*)alloc((size_t)DH_ * DH_ * 2);
    unsigned short* wqkvt = (unsigned short*)alloc((size_t)DH_ * DH_ * 3 * 2);
    unsigned short* wot   = (unsigned short*)alloc((size_t)DH_ * DH_ * 2);
    unsigned short* wf1t  = (unsigned short*)alloc((size_t)DH_ * DFF_ * 2);
    unsigned short* wf2t  = (unsigned short*)alloc((size_t)DFF_ * DH_ * 2);
    unsigned short* Xa   = Arena;                            // NN*DIN (4M)
    unsigned short* X2a  = Arena + (size_t)NN * DIN_;        // [4M..12M)
    unsigned short* QKVb = Arena;                            // [0..24M)
    unsigned short* Fb   = Arena;                            // [0..32M)
    unsigned short* tb   = TB;

    // ONE memset for deg+cnt+all 4 stat arrays (contiguous, 256-aligned).
    hipMemsetAsync(deg, 0, 2 * NN * 4 + 4 * 1024, stream);

    // MEGA-PREP: weight transposes + bias concat + deg histogram + initstats.
    PrepArgs pa;
    pa.w[0] = w_conv1; pa.o[0] = wc1t;                pa.K[0] = DIN_; pa.N[0] = DH_;  pa.s[0] = 1.f;
    pa.w[1] = w_conv2; pa.o[1] = wc2t;                pa.K[1] = DH_;  pa.N[1] = DH_;  pa.s[1] = 1.f;
    pa.w[2] = wq;      pa.o[2] = wqkvt;               pa.K[2] = DH_;  pa.N[2] = DH_;  pa.s[2] = QSCALE;
    pa.w[3] = wk;      pa.o[3] = wqkvt + DH_ * DH_;   pa.K[3] = DH_;  pa.N[3] = DH_;  pa.s[3] = 1.f;
    pa.w[4] = wv;      pa.o[4] = wqkvt + 2 * DH_ * DH_; pa.K[4] = DH_; pa.N[4] = DH_; pa.s[4] = 1.f;
    pa.w[5] = wo;      pa.o[5] = wot;                 pa.K[5] = DH_;  pa.N[5] = DH_;  pa.s[5] = 1.f;
    pa.w[6] = w_ff1;   pa.o[6] = wf1t;                pa.K[6] = DH_;  pa.N[6] = DFF_; pa.s[6] = 1.f;
    pa.w[7] = w_ff2;   pa.o[7] = wf2t;                pa.K[7] = DFF_; pa.N[7] = DH_;  pa.s[7] = 1.f;
    pa.bq = bq; pa.bk = bk; pa.bv = bv; pa.bqkv = bqkv;
    pa.col = ei + EE; pa.deg = deg;
    pa.X = x; pa.out2 = out + BG * DH_; pa.outz = out;
    pa.csum = csum; pa.csumsq = csumsq;
    prep_kernel<<<dim3(EE / 256, 11), 256, 0, stream>>>(pa);

    // Fused CSR scan (block 0) + BN1 apply (blocks 1..1024)
    scanbn_kernel<<<1 + NN * DIN_ / 4096, 1024, 0, stream>>>(
        deg, off, dis, x, csum, csumsq, bn1_g, bn1_b, B0);

    scatter_kernel<<<EE / 256, 256, 0, stream>>>(ei, ei + EE, off, cnt, srow);

    // agg1 (A·X)·W == A·(X·W): Xa = Anorm @ Xb (bf16, 128 cols)
    aggb_kernel<DIN_, 0><<<NN / 4, 256, 0, stream>>>(B0, off, srow, dis,
                                                     nullptr, nullptr, nullptr,
                                                     nullptr, Xa);
    // conv1 (MODE 1): h1b = relu(Xa @ w_conv1 + b) -> B0 ; fused BN2 stats
    gemm64n256_kernel<1><<<NN / 64, 512, 0, stream>>>(
        Xa, wc1t, B0, DIN_, b_conv1, nullptr, nullptr, 1, 0,
        csum2, csumsq2, nullptr, nullptr, nullptr);

    // agg2 with fused BN apply (inline stats finalization)
    aggb_kernel<DH_, 1><<<NN / 4, 256, 0, stream>>>(B0, off, srow, dis,
                                                    csum2, csumsq2, bn2_g, bn2_b,
                                                    X2a);
    // conv2 (MODE 0): tb = h1b + relu(X2a @ w_conv2 + b) + inter[graph] -> TB
    gemm64n256_kernel<0><<<NN / 64, 512, 0, stream>>>(
        X2a, wc2t, tb, DH_, b_conv2, B0, inter_f, 1, 1,
        nullptr, nullptr, nullptr, nullptr, nullptr);

    // Fused QKV (N=768, MT=128): QKVb = tb @ [wq*s|wk|wv] + bqkv
    gemm_bf16_kernel<<<dim3(768 / 128, NN / 128), 512, 0, stream>>>(
        tb, wqkvt, QKVb, NN, DH_, 768, bqkv, nullptr, nullptr, 0, 0);

    // MFMA flash attention -> Ob (B0; h1b dead)
    attn_mfma_kernel<<<BG * NH, 256, 0, stream>>>(QKVb, B0);

    // O-proj (MODE 2): t2b = LN1(Ob @ wo + bo + tb) -> B0 in-place
    gemm64n256_kernel<2><<<NN / 64, 512, 0, stream>>>(
        B0, wot, B0, DH_, bo, tb, nullptr, 0, 0,
        nullptr, nullptr, ln1_g, ln1_b, nullptr);

    // ff1 (N=1024, MT=128): Fb = relu(t2b @ w_ff1 + b1)
    gemm_bf16_kernel<<<dim3(DFF_ / 128, NN / 128), 512, 0, stream>>>(
        B0, wf1t, Fb, NN, DH_, DFF_, b_ff1, nullptr, nullptr, 1, 0);

    // ff2 (MODE 3): LN2(Fb @ w_ff2 + b2 + t2b) -> per-graph column sums -> out
    gemm64n256_kernel<3><<<NN / 64, 512, 0, stream>>>(
        Fb, wf2t, nullptr, DFF_, b_ff2, B0, nullptr, 0, 0,
        nullptr, nullptr, ln2_g, ln2_b, out);
}